// Round 17
// baseline (163.964 us; speedup 1.0000x reference)
//
#include <hip/hip_runtime.h>
#include <hip/hip_bf16.h>

typedef __attribute__((ext_vector_type(8))) short bf16x8;
typedef __attribute__((ext_vector_type(4))) float f32x4;
typedef unsigned short u16;

#define DEVI __device__ __forceinline__

DEVI u16 f2bf(float f){
  unsigned int u = __float_as_uint(f);
  u += 0x7FFF + ((u >> 16) & 1);
  return (u16)(u >> 16);
}

// RNE bf16 pair pack: {hi:bf(b), lo:bf(a)} — bit-identical to shift-OR of f2bf.
DEVI unsigned int bfpack(float a, float b){
  unsigned int ua = __float_as_uint(a), ub = __float_as_uint(b);
  ua += 0x7FFF + ((ua >> 16) & 1);
  ub += 0x7FFF + ((ub >> 16) & 1);
  return __builtin_amdgcn_perm(ub, ua, 0x07060302u);
}

// TRUNCATION bf16 pair pack: {hi:trunc-bf(b), lo:trunc-bf(a)} — single v_perm.
// Used ONLY for P: l is computed from the same truncated P (ones-MFMA), so
// the common-mode truncation bias cancels exactly in the P/l ratio.
DEVI unsigned int bfpack_tr(float a, float b){
  return __builtin_amdgcn_perm(__float_as_uint(b), __float_as_uint(a), 0x07060302u);
}

DEVI float fast_exp2(float x){
#if __has_builtin(__builtin_amdgcn_exp2f)
  return __builtin_amdgcn_exp2f(x);
#else
  return exp2f(x);
#endif
}

// async global->LDS, 16B per lane; LDS dest = wave-uniform base + lane*16
DEVI void gload16(const u16* g, u16* l){
  __builtin_amdgcn_global_load_lds((const __attribute__((address_space(1))) void*)g,
                                   (__attribute__((address_space(3))) void*)l, 16, 0, 0);
}

// ---------------- prep kernels ----------------

// hs f32 -> bf16 conversion; first 131072 threads also fill the rope table
// cs[s*64+d] = {cos, sin} of s * 10000^(-(d%32)/32).  [s][d] layout: epilogue
// loads have d = li varying across lanes -> 128B-contiguous per 16-lane group.
__global__ __launch_bounds__(256) void k_conv_hs(const float* __restrict__ src,
                                                 u16* __restrict__ dst, int n4,
                                                 float2* __restrict__ cs){
  int idx = blockIdx.x * blockDim.x + threadIdx.x;
  int stride = gridDim.x * blockDim.x;
  for (int i = idx; i < n4; i += stride){
    float4 v = ((const float4*)src)[i];
    ushort4 o;
    o.x = f2bf(v.x); o.y = f2bf(v.y); o.z = f2bf(v.z); o.w = f2bf(v.w);
    ((ushort4*)dst)[i] = o;
  }
  if (idx < 131072){                       // 2048*64 rope entries
    int d = idx & 63, s = idx >> 6;
    int i = d & 31;
    float invf = __expf(-(float)i / 32.f * 9.210340371976184f);
    float ang = (float)s * invf;
    cs[idx] = make_float2(cosf(ang), sinf(ang));
  }
}

// W [k][n] f32  ->  Wt [n][k] bf16   (3 matrices)
__global__ __launch_bounds__(256) void k_trans_w(const float* __restrict__ w0,
    const float* __restrict__ w1, const float* __restrict__ w2, u16* __restrict__ Wt){
  __shared__ float t[32][33];
  int z = blockIdx.z;
  const float* W = z == 0 ? w0 : (z == 1 ? w1 : w2);
  u16* dst = Wt + z * 1048576;
  int tx = threadIdx.x, ty = threadIdx.y;
  int n = blockIdx.x * 32 + tx;
  for (int j = 0; j < 4; ++j){
    int k = blockIdx.y * 32 + ty + j * 8;
    t[ty + j * 8][tx] = W[k * 1024 + n];
  }
  __syncthreads();
  for (int j = 0; j < 4; ++j){
    int nrow = blockIdx.x * 32 + ty + j * 8;
    int kcol = blockIdx.y * 32 + tx;
    dst[nrow * 1024 + kcol] = f2bf(t[tx][ty + j * 8]);
  }
}

// ---------------- QKV projection GEMM ----------------
// m97 structure + bijective XCD swizzle (T1): each XCD owns an 8-m-tile strip
// (2MB A, L2-resident); within XCD iterate m fastest, then n, then which.
__global__ __launch_bounds__(256) void k_qkv(const u16* __restrict__ hsb,
    const u16* __restrict__ Wt, const float* __restrict__ biasq,
    const float* __restrict__ biask, const float* __restrict__ biasv,
    const float2* __restrict__ cs,
    u16* __restrict__ Qb, u16* __restrict__ Kb, u16* __restrict__ Vt){
  __shared__ u16 At[128 * 64];
  __shared__ u16 Bt[128 * 64];
  // lin = x + 8y + 512z; xcd = lin&7 (HW round-robin); q orders blocks in time
  int lin = blockIdx.x + (blockIdx.y << 3) + (blockIdx.z << 9);
  int xcd = lin & 7, q = lin >> 3;
  int mi_ = q & 7, rest = q >> 3;
  int which = rest >> 3;
  int m0 = (xcd * 8 + mi_) * 128;
  int n0 = (rest & 7) * 128;
  const u16* Wb = Wt + which * 1048576;
  int tid = threadIdx.x, lane = tid & 63, wid = tid >> 6, g = lane >> 4, li = lane & 15;
  int wrow = (wid >> 1) * 64, wcol = (wid & 1) * 64;
  int kvr = lane >> 3;            // row within an 8-row segment
  int gsl = (lane & 7) ^ kvr;     // pre-swizzled 16B slot in the 128B row
  f32x4 zero = {0.f, 0.f, 0.f, 0.f};
  f32x4 acc[4][4];
  for (int i = 0; i < 4; ++i) for (int j = 0; j < 4; ++j) acc[i][j] = zero;

  for (int kt = 0; kt < 16; ++kt){
    #pragma unroll
    for (int i = 0; i < 4; ++i){
      int seg = wid * 4 + i;             // 0..15, 8 rows each
      int row = seg * 8 + kvr;
      gload16(hsb + (m0 + row) * 1024 + kt * 64 + gsl * 8, At + seg * 512);
      gload16(Wb  + (n0 + row) * 1024 + kt * 64 + gsl * 8, Bt + seg * 512);
    }
    __syncthreads();                     // drains vmcnt -> tiles ready
    #pragma unroll
    for (int kk = 0; kk < 2; ++kk){
      bf16x8 af[4], bfr[4];
      #pragma unroll
      for (int i = 0; i < 4; ++i){
        int row = wrow + i * 16 + li;
        af[i] = *(const bf16x8*)((char*)At + row * 128 + ((kk * 64 + g * 16) ^ ((row & 7) << 4)));
        int col = wcol + i * 16 + li;
        bfr[i] = *(const bf16x8*)((char*)Bt + col * 128 + ((kk * 64 + g * 16) ^ ((col & 7) << 4)));
      }
      #pragma unroll
      for (int i = 0; i < 4; ++i)
        #pragma unroll
        for (int j = 0; j < 4; ++j)
          acc[i][j] = __builtin_amdgcn_mfma_f32_16x16x32_bf16(af[i], bfr[j], acc[i][j], 0, 0, 0);
    }
    __syncthreads();                     // all reads done before next stage
  }

  // epilogue
  const float* bias = which == 0 ? biasq : (which == 1 ? biask : biasv);
  int b = m0 >> 11;                      // batch (block never straddles)
  int hbase = (n0 + wcol) >> 6;          // head
  float vals[4][4][4];
  for (int i = 0; i < 4; ++i)
    for (int j = 0; j < 4; ++j){
      float bb = bias[n0 + wcol + j * 16 + li];
      for (int r = 0; r < 4; ++r){
        float v = acc[i][j][r] + bb;
        // q: hd^-0.5 pre-scale * 1/sqrt(hd) * log2(e)  (exp -> exp2 downstream)
        if (which == 0) v *= 0.015625f * 1.4426950408889634f;
        vals[i][j][r] = v;
      }
    }
  if (which < 2){
    u16* dst = which == 0 ? Qb : Kb;
    for (int i = 0; i < 4; ++i)
      for (int j = 0; j < 4; ++j)
        for (int r = 0; r < 4; ++r){
          int m = m0 + wrow + i * 16 + g * 4 + r;
          int srow = m & 2047;
          int d = j * 16 + li;
          float2 c2 = cs[srow * 64 + d];
          float part = vals[i][j ^ 2][r];           // partner col d^32 (same lane)
          float o = vals[i][j][r] * c2.x + (d < 32 ? -part : part) * c2.y;
          dst[(((long)b * 16 + hbase) * 2048 + srow) * 64 + d] = f2bf(o);
        }
  } else {
    for (int i = 0; i < 4; ++i)
      for (int j = 0; j < 4; ++j){
        int sbase = (m0 + wrow + i * 16 + g * 4) & 2047;
        int d = j * 16 + li;
        ushort4 pk;
        pk.x = f2bf(vals[i][j][0]); pk.y = f2bf(vals[i][j][1]);
        pk.z = f2bf(vals[i][j][2]); pk.w = f2bf(vals[i][j][3]);
        *(ushort4*)(Vt + (((long)b * 16 + hbase) * 64 + d) * 2048 + sbase) = pk;
      }
  }
}

// ---------------- attention ----------------
// Round-16 structure (counted-vmcnt two-barrier schedule) + t-loop unroll 2:
// with cur compile-time-constant per unrolled copy, all KT/VT/PT addresses
// are loop-invariant and hoisted -- cuts the ~2/3 of VALU issue that was
// per-tile address recomputation. Zero semantic change (absmax bit-identical
// canary). Unnormalized softmax, exp2 with folded log2e, truncation P-pack,
// K+V via global_load_lds double-buffered, l via ones-row MFMA.
__global__ __launch_bounds__(256, 4) void k_attn(const u16* __restrict__ Qb,
    const u16* __restrict__ Kb, const u16* __restrict__ Vt, float* __restrict__ out){
  __shared__ u16 KT[2][64 * 64];      // [buf][kv(64)][d(64)]  8KB each
  __shared__ u16 VT[2][64 * 64];      // [buf][d(64)][kv(64)]  8KB each
  __shared__ u16 PT[4][1024];         // per wave: [q(16)][kv(64)] 2KB, shared mi
  // XCD swizzle: all 16 q-tile blocks of one head land on one XCD
  int lin = blockIdx.y * 16 + blockIdx.x;
  int swzb = ((lin & 7) << 7) + (lin >> 3);
  int qt = swzb & 15, bh = swzb >> 4;
  int tid = threadIdx.x, lane = tid & 63, w = tid >> 6, g = lane >> 4, li = lane & 15;
  int swm = (li & 7) << 4;
  int kvr = lane >> 3;
  int gsl = (lane & 7) ^ kvr;
  int seg0 = w * 2, seg1 = w * 2 + 1;

  const u16* Qp = Qb + ((long)bh * 2048 + qt * 128 + w * 32) * 64;
  bf16x8 qa00 = *(const bf16x8*)(Qp + li * 64 + g * 8);
  bf16x8 qa01 = *(const bf16x8*)(Qp + li * 64 + 32 + g * 8);
  bf16x8 qa10 = *(const bf16x8*)(Qp + (16 + li) * 64 + g * 8);
  bf16x8 qa11 = *(const bf16x8*)(Qp + (16 + li) * 64 + 32 + g * 8);

  const u16* Kp = Kb + (long)bh * 131072;
  const u16* Vp = Vt + (long)bh * 131072;

  f32x4 zero = {0.f, 0.f, 0.f, 0.f};
  f32x4 oc[4][2];
  for (int i = 0; i < 4; ++i){ oc[i][0] = zero; oc[i][1] = zero; }
  f32x4 lacc0 = zero, lacc1 = zero;   // ones-row MFMA accumulators (l for q=li)
  bf16x8 ones;
  #pragma unroll
  for (int i = 0; i < 8; ++i) ones[i] = (short)0x3F80;  // bf16 1.0

  auto STAGE = [&](int t, int c){
    const u16* kbase = Kp + t * 4096;
    const u16* vbase = Vp + t * 64;
    gload16(kbase + (seg0 * 8 + kvr) * 64 + gsl * 8, &KT[c][seg0 * 512]);
    gload16(kbase + (seg1 * 8 + kvr) * 64 + gsl * 8, &KT[c][seg1 * 512]);
    gload16(vbase + (seg0 * 8 + kvr) * 2048 + gsl * 8, &VT[c][seg0 * 512]);
    gload16(vbase + (seg1 * 8 + kvr) * 2048 + gsl * 8, &VT[c][seg1 * 512]);
  };

  STAGE(0, 0);

  #pragma unroll 2
  for (int t = 0; t < 32; ++t){
    int cur = t & 1;
    if (t < 31){
      STAGE(t + 1, cur ^ 1);
      // wait for OWN stage(t) (issued a full tile ago); stage(t+1) stays in flight
      asm volatile("s_waitcnt vmcnt(4)" ::: "memory");
    } else {
      asm volatile("s_waitcnt vmcnt(0)" ::: "memory");
    }
    asm volatile("s_barrier" ::: "memory");   // A: all waves' stage(t) landed

    const char* Kc = (const char*)&KT[cur][0];
    const char* Vc = (const char*)&VT[cur][0];

    // QK^T (swapped): sc[mi][ni][r] = S'[kv = ni*16+g*4+r][q = li]
    f32x4 sc[2][4];
    __builtin_amdgcn_s_setprio(1);
    #pragma unroll
    for (int ni = 0; ni < 4; ++ni){
      const char* kr = Kc + (ni * 16 + li) * 128;
      bf16x8 k0 = *(const bf16x8*)(kr + ((g * 16) ^ swm));
      bf16x8 k1 = *(const bf16x8*)(kr + ((64 + g * 16) ^ swm));
      f32x4 a0 = zero, a1 = zero;
      a0 = __builtin_amdgcn_mfma_f32_16x16x32_bf16(k0, qa00, a0, 0, 0, 0);
      a0 = __builtin_amdgcn_mfma_f32_16x16x32_bf16(k1, qa01, a0, 0, 0, 0);
      a1 = __builtin_amdgcn_mfma_f32_16x16x32_bf16(k0, qa10, a1, 0, 0, 0);
      a1 = __builtin_amdgcn_mfma_f32_16x16x32_bf16(k1, qa11, a1, 0, 0, 0);
      sc[0][ni] = a0; sc[1][ni] = a1;
    }
    __builtin_amdgcn_s_setprio(0);

    // per-panel: P = exp2(S') -> truncation pack -> per-wave LDS -> P frags
    char* pbase = (char*)&PT[w][0];
    bf16x8 pbr0[2], pbr1[2];
    #pragma unroll
    for (int mi = 0; mi < 2; ++mi){
      char* pbw = pbase + li * 128;
      #pragma unroll
      for (int ni = 0; ni < 4; ++ni){
        float p0 = fast_exp2(sc[mi][ni][0]);
        float p1 = fast_exp2(sc[mi][ni][1]);
        float p2 = fast_exp2(sc[mi][ni][2]);
        float p3 = fast_exp2(sc[mi][ni][3]);
        uint2 u;
        u.x = bfpack_tr(p0, p1);
        u.y = bfpack_tr(p2, p3);
        *(uint2*)(pbw + ((ni * 32 + g * 8) ^ swm)) = u;   // ds_write_b64
      }
      // read this panel's B-frags before next panel overwrites the buffer
      // (same-wave DS ops execute in order)
      if (mi == 0){
        pbr0[0] = *(const bf16x8*)(pbase + li * 128 + ((g * 16) ^ swm));
        pbr0[1] = *(const bf16x8*)(pbase + li * 128 + ((64 + g * 16) ^ swm));
      } else {
        pbr1[0] = *(const bf16x8*)(pbase + li * 128 + ((g * 16) ^ swm));
        pbr1[1] = *(const bf16x8*)(pbase + li * 128 + ((64 + g * 16) ^ swm));
      }
    }

    // PV: ctx^T += V^T . P^T  (V frags read once, used by both panels);
    // l += ones . P^T
    __builtin_amdgcn_s_setprio(1);
    #pragma unroll
    for (int kk = 0; kk < 2; ++kk){
      bf16x8 pb0 = kk ? pbr0[1] : pbr0[0];
      bf16x8 pb1 = kk ? pbr1[1] : pbr1[0];
      lacc0 = __builtin_amdgcn_mfma_f32_16x16x32_bf16(ones, pb0, lacc0, 0, 0, 0);
      lacc1 = __builtin_amdgcn_mfma_f32_16x16x32_bf16(ones, pb1, lacc1, 0, 0, 0);
      #pragma unroll
      for (int md = 0; md < 4; ++md){
        int d = md * 16 + li;
        bf16x8 va = *(const bf16x8*)(Vc + d * 128 + ((kk * 64 + g * 16) ^ ((d & 7) << 4)));
        oc[md][0] = __builtin_amdgcn_mfma_f32_16x16x32_bf16(va, pb0, oc[md][0], 0, 0, 0);
        oc[md][1] = __builtin_amdgcn_mfma_f32_16x16x32_bf16(va, pb1, oc[md][1], 0, 0, 0);
      }
    }
    __builtin_amdgcn_s_setprio(0);
    asm volatile("s_waitcnt lgkmcnt(0)" ::: "memory");  // my LDS reads complete
    asm volatile("s_barrier" ::: "memory");   // B: safe to overwrite KT/VT[cur]
  }

  // epilogue: ctx^T (row=d, col=q=li), scale by 1/l (all lacc regs equal)
  float rl0 = 1.f / lacc0[0], rl1 = 1.f / lacc1[0];
  int b = bh >> 4, h = bh & 15;
  long obase = ((long)b * 2048 + qt * 128 + w * 32) * 1024 + h * 64;
  #pragma unroll
  for (int md = 0; md < 4; ++md){
    int d0 = md * 16 + g * 4;
    f32x4 v0 = oc[md][0] * rl0;
    f32x4 v1 = oc[md][1] * rl1;
    *(f32x4*)(out + obase + (long)li * 1024 + d0) = v0;
    *(f32x4*)(out + obase + (long)(16 + li) * 1024 + d0) = v1;
  }
}

// ---------------- launch ----------------
extern "C" void kernel_launch(void* const* d_in, const int* in_sizes, int n_in,
                              void* d_out, int out_size, void* d_ws, size_t ws_size,
                              hipStream_t stream){
  const float* hs  = (const float*)d_in[0];
  const float* Wq  = (const float*)d_in[1];
  const float* bq  = (const float*)d_in[2];
  const float* Wk  = (const float*)d_in[3];
  const float* bk  = (const float*)d_in[4];
  const float* Wv  = (const float*)d_in[5];
  const float* bvv = (const float*)d_in[6];
  float* out = (float*)d_out;
  char* ws = (char*)d_ws;

  u16*    hsb = (u16*)(ws);                 // 16 MB  bf16 hidden
  u16*    Wt  = (u16*)(ws + 16777216);      //  6 MB  bf16 W^T x3
  u16*    Qb  = (u16*)(ws + 23068672);      // 16 MB  Q  [bh][s][d]
  u16*    Kb  = (u16*)(ws + 39845888);      // 16 MB  K  [bh][s][d]
  u16*    Vt  = (u16*)(ws + 56623104);      // 16 MB  V^T[bh][d][s]
  float2* cs  = (float2*)(ws + 73400320);   //  1 MB  rope table

  k_conv_hs<<<dim3(2048), dim3(256), 0, stream>>>(hs, hsb, 2097152, cs);
  k_trans_w<<<dim3(32, 32, 3), dim3(32, 8), 0, stream>>>(Wq, Wk, Wv, Wt);
  k_qkv<<<dim3(8, 64, 3), dim3(256), 0, stream>>>(hsb, Wt, bq, bk, bvv, cs, Qb, Kb, Vt);
  k_attn<<<dim3(16, 64), dim3(256), 0, stream>>>(Qb, Kb, Vt, out);
}

// Round 18
// 163.579 us; speedup vs baseline: 1.0024x; 1.0024x over previous
//
#include <hip/hip_runtime.h>
#include <hip/hip_bf16.h>

typedef __attribute__((ext_vector_type(8))) short bf16x8;
typedef __attribute__((ext_vector_type(4))) float f32x4;
typedef unsigned short u16;

#define DEVI __device__ __forceinline__

DEVI u16 f2bf(float f){
  unsigned int u = __float_as_uint(f);
  u += 0x7FFF + ((u >> 16) & 1);
  return (u16)(u >> 16);
}

// RNE bf16 pair pack: {hi:bf(b), lo:bf(a)} — bit-identical to shift-OR of f2bf.
DEVI unsigned int bfpack(float a, float b){
  unsigned int ua = __float_as_uint(a), ub = __float_as_uint(b);
  ua += 0x7FFF + ((ua >> 16) & 1);
  ub += 0x7FFF + ((ub >> 16) & 1);
  return __builtin_amdgcn_perm(ub, ua, 0x07060302u);
}

// TRUNCATION bf16 pair pack: {hi:trunc-bf(b), lo:trunc-bf(a)} — single v_perm.
// Used ONLY for P: l is computed from the same truncated P (ones-MFMA), so
// the common-mode truncation bias cancels exactly in the P/l ratio.
DEVI unsigned int bfpack_tr(float a, float b){
  return __builtin_amdgcn_perm(__float_as_uint(b), __float_as_uint(a), 0x07060302u);
}

DEVI float fast_exp2(float x){
#if __has_builtin(__builtin_amdgcn_exp2f)
  return __builtin_amdgcn_exp2f(x);
#else
  return exp2f(x);
#endif
}

// async global->LDS, 16B per lane; LDS dest = wave-uniform base + lane*16
DEVI void gload16(const u16* g, u16* l){
  __builtin_amdgcn_global_load_lds((const __attribute__((address_space(1))) void*)g,
                                   (__attribute__((address_space(3))) void*)l, 16, 0, 0);
}

// ---------------- prep kernels ----------------

// hs f32 -> bf16 conversion; first 131072 threads also fill the rope table
// cs[s*64+d] = {cos, sin} of s * 10000^(-(d%32)/32).  [s][d] layout: epilogue
// loads have d = li varying across lanes -> 128B-contiguous per 16-lane group.
__global__ __launch_bounds__(256) void k_conv_hs(const float* __restrict__ src,
                                                 u16* __restrict__ dst, int n4,
                                                 float2* __restrict__ cs){
  int idx = blockIdx.x * blockDim.x + threadIdx.x;
  int stride = gridDim.x * blockDim.x;
  for (int i = idx; i < n4; i += stride){
    float4 v = ((const float4*)src)[i];
    ushort4 o;
    o.x = f2bf(v.x); o.y = f2bf(v.y); o.z = f2bf(v.z); o.w = f2bf(v.w);
    ((ushort4*)dst)[i] = o;
  }
  if (idx < 131072){                       // 2048*64 rope entries
    int d = idx & 63, s = idx >> 6;
    int i = d & 31;
    float invf = __expf(-(float)i / 32.f * 9.210340371976184f);
    float ang = (float)s * invf;
    cs[idx] = make_float2(cosf(ang), sinf(ang));
  }
}

// W [k][n] f32  ->  Wt [n][k] bf16   (3 matrices)
__global__ __launch_bounds__(256) void k_trans_w(const float* __restrict__ w0,
    const float* __restrict__ w1, const float* __restrict__ w2, u16* __restrict__ Wt){
  __shared__ float t[32][33];
  int z = blockIdx.z;
  const float* W = z == 0 ? w0 : (z == 1 ? w1 : w2);
  u16* dst = Wt + z * 1048576;
  int tx = threadIdx.x, ty = threadIdx.y;
  int n = blockIdx.x * 32 + tx;
  for (int j = 0; j < 4; ++j){
    int k = blockIdx.y * 32 + ty + j * 8;
    t[ty + j * 8][tx] = W[k * 1024 + n];
  }
  __syncthreads();
  for (int j = 0; j < 4; ++j){
    int nrow = blockIdx.x * 32 + ty + j * 8;
    int kcol = blockIdx.y * 32 + tx;
    dst[nrow * 1024 + kcol] = f2bf(t[tx][ty + j * 8]);
  }
}

// ---------------- QKV projection GEMM ----------------
// m97 structure + bijective XCD swizzle (T1): each XCD owns an 8-m-tile strip
// (2MB A, L2-resident); within XCD iterate m fastest, then n, then which.
__global__ __launch_bounds__(256) void k_qkv(const u16* __restrict__ hsb,
    const u16* __restrict__ Wt, const float* __restrict__ biasq,
    const float* __restrict__ biask, const float* __restrict__ biasv,
    const float2* __restrict__ cs,
    u16* __restrict__ Qb, u16* __restrict__ Kb, u16* __restrict__ Vt){
  __shared__ u16 At[128 * 64];
  __shared__ u16 Bt[128 * 64];
  // lin = x + 8y + 512z; xcd = lin&7 (HW round-robin); q orders blocks in time
  int lin = blockIdx.x + (blockIdx.y << 3) + (blockIdx.z << 9);
  int xcd = lin & 7, q = lin >> 3;
  int mi_ = q & 7, rest = q >> 3;
  int which = rest >> 3;
  int m0 = (xcd * 8 + mi_) * 128;
  int n0 = (rest & 7) * 128;
  const u16* Wb = Wt + which * 1048576;
  int tid = threadIdx.x, lane = tid & 63, wid = tid >> 6, g = lane >> 4, li = lane & 15;
  int wrow = (wid >> 1) * 64, wcol = (wid & 1) * 64;
  int kvr = lane >> 3;            // row within an 8-row segment
  int gsl = (lane & 7) ^ kvr;     // pre-swizzled 16B slot in the 128B row
  f32x4 zero = {0.f, 0.f, 0.f, 0.f};
  f32x4 acc[4][4];
  for (int i = 0; i < 4; ++i) for (int j = 0; j < 4; ++j) acc[i][j] = zero;

  for (int kt = 0; kt < 16; ++kt){
    #pragma unroll
    for (int i = 0; i < 4; ++i){
      int seg = wid * 4 + i;             // 0..15, 8 rows each
      int row = seg * 8 + kvr;
      gload16(hsb + (m0 + row) * 1024 + kt * 64 + gsl * 8, At + seg * 512);
      gload16(Wb  + (n0 + row) * 1024 + kt * 64 + gsl * 8, Bt + seg * 512);
    }
    __syncthreads();                     // drains vmcnt -> tiles ready
    #pragma unroll
    for (int kk = 0; kk < 2; ++kk){
      bf16x8 af[4], bfr[4];
      #pragma unroll
      for (int i = 0; i < 4; ++i){
        int row = wrow + i * 16 + li;
        af[i] = *(const bf16x8*)((char*)At + row * 128 + ((kk * 64 + g * 16) ^ ((row & 7) << 4)));
        int col = wcol + i * 16 + li;
        bfr[i] = *(const bf16x8*)((char*)Bt + col * 128 + ((kk * 64 + g * 16) ^ ((col & 7) << 4)));
      }
      #pragma unroll
      for (int i = 0; i < 4; ++i)
        #pragma unroll
        for (int j = 0; j < 4; ++j)
          acc[i][j] = __builtin_amdgcn_mfma_f32_16x16x32_bf16(af[i], bfr[j], acc[i][j], 0, 0, 0);
    }
    __syncthreads();                     // all reads done before next stage
  }

  // epilogue
  const float* bias = which == 0 ? biasq : (which == 1 ? biask : biasv);
  int b = m0 >> 11;                      // batch (block never straddles)
  int hbase = (n0 + wcol) >> 6;          // head
  float vals[4][4][4];
  for (int i = 0; i < 4; ++i)
    for (int j = 0; j < 4; ++j){
      float bb = bias[n0 + wcol + j * 16 + li];
      for (int r = 0; r < 4; ++r){
        float v = acc[i][j][r] + bb;
        // q: hd^-0.5 pre-scale * 1/sqrt(hd) * log2(e)  (exp -> exp2 downstream)
        if (which == 0) v *= 0.015625f * 1.4426950408889634f;
        vals[i][j][r] = v;
      }
    }
  if (which < 2){
    u16* dst = which == 0 ? Qb : Kb;
    for (int i = 0; i < 4; ++i)
      for (int j = 0; j < 4; ++j)
        for (int r = 0; r < 4; ++r){
          int m = m0 + wrow + i * 16 + g * 4 + r;
          int srow = m & 2047;
          int d = j * 16 + li;
          float2 c2 = cs[srow * 64 + d];
          float part = vals[i][j ^ 2][r];           // partner col d^32 (same lane)
          float o = vals[i][j][r] * c2.x + (d < 32 ? -part : part) * c2.y;
          dst[(((long)b * 16 + hbase) * 2048 + srow) * 64 + d] = f2bf(o);
        }
  } else {
    for (int i = 0; i < 4; ++i)
      for (int j = 0; j < 4; ++j){
        int sbase = (m0 + wrow + i * 16 + g * 4) & 2047;
        int d = j * 16 + li;
        ushort4 pk;
        pk.x = f2bf(vals[i][j][0]); pk.y = f2bf(vals[i][j][1]);
        pk.z = f2bf(vals[i][j][2]); pk.w = f2bf(vals[i][j][3]);
        *(ushort4*)(Vt + (((long)b * 16 + hbase) * 64 + d) * 2048 + sbase) = pk;
      }
  }
}

// ---------------- attention ----------------
// Round-16 structure (counted-vmcnt two-barrier schedule) + t-loop unroll 2:
// with cur compile-time-constant per unrolled copy, all KT/VT/PT addresses
// are loop-invariant and hoisted -- cuts the ~2/3 of VALU issue that was
// per-tile address recomputation. Zero semantic change (absmax bit-identical
// canary). Unnormalized softmax, exp2 with folded log2e, truncation P-pack,
// K+V via global_load_lds double-buffered, l via ones-row MFMA.
__global__ __launch_bounds__(256, 4) void k_attn(const u16* __restrict__ Qb,
    const u16* __restrict__ Kb, const u16* __restrict__ Vt, float* __restrict__ out){
  __shared__ u16 KT[2][64 * 64];      // [buf][kv(64)][d(64)]  8KB each
  __shared__ u16 VT[2][64 * 64];      // [buf][d(64)][kv(64)]  8KB each
  __shared__ u16 PT[4][1024];         // per wave: [q(16)][kv(64)] 2KB, shared mi
  // XCD swizzle: all 16 q-tile blocks of one head land on one XCD
  int lin = blockIdx.y * 16 + blockIdx.x;
  int swzb = ((lin & 7) << 7) + (lin >> 3);
  int qt = swzb & 15, bh = swzb >> 4;
  int tid = threadIdx.x, lane = tid & 63, w = tid >> 6, g = lane >> 4, li = lane & 15;
  int swm = (li & 7) << 4;
  int kvr = lane >> 3;
  int gsl = (lane & 7) ^ kvr;
  int seg0 = w * 2, seg1 = w * 2 + 1;

  const u16* Qp = Qb + ((long)bh * 2048 + qt * 128 + w * 32) * 64;
  bf16x8 qa00 = *(const bf16x8*)(Qp + li * 64 + g * 8);
  bf16x8 qa01 = *(const bf16x8*)(Qp + li * 64 + 32 + g * 8);
  bf16x8 qa10 = *(const bf16x8*)(Qp + (16 + li) * 64 + g * 8);
  bf16x8 qa11 = *(const bf16x8*)(Qp + (16 + li) * 64 + 32 + g * 8);

  const u16* Kp = Kb + (long)bh * 131072;
  const u16* Vp = Vt + (long)bh * 131072;

  f32x4 zero = {0.f, 0.f, 0.f, 0.f};
  f32x4 oc[4][2];
  for (int i = 0; i < 4; ++i){ oc[i][0] = zero; oc[i][1] = zero; }
  f32x4 lacc0 = zero, lacc1 = zero;   // ones-row MFMA accumulators (l for q=li)
  bf16x8 ones;
  #pragma unroll
  for (int i = 0; i < 8; ++i) ones[i] = (short)0x3F80;  // bf16 1.0

  auto STAGE = [&](int t, int c){
    const u16* kbase = Kp + t * 4096;
    const u16* vbase = Vp + t * 64;
    gload16(kbase + (seg0 * 8 + kvr) * 64 + gsl * 8, &KT[c][seg0 * 512]);
    gload16(kbase + (seg1 * 8 + kvr) * 64 + gsl * 8, &KT[c][seg1 * 512]);
    gload16(vbase + (seg0 * 8 + kvr) * 2048 + gsl * 8, &VT[c][seg0 * 512]);
    gload16(vbase + (seg1 * 8 + kvr) * 2048 + gsl * 8, &VT[c][seg1 * 512]);
  };

  STAGE(0, 0);

  #pragma unroll 2
  for (int t = 0; t < 32; ++t){
    int cur = t & 1;
    if (t < 31){
      STAGE(t + 1, cur ^ 1);
      // wait for OWN stage(t) (issued a full tile ago); stage(t+1) stays in flight
      asm volatile("s_waitcnt vmcnt(4)" ::: "memory");
    } else {
      asm volatile("s_waitcnt vmcnt(0)" ::: "memory");
    }
    asm volatile("s_barrier" ::: "memory");   // A: all waves' stage(t) landed

    const char* Kc = (const char*)&KT[cur][0];
    const char* Vc = (const char*)&VT[cur][0];

    // QK^T (swapped): sc[mi][ni][r] = S'[kv = ni*16+g*4+r][q = li]
    f32x4 sc[2][4];
    __builtin_amdgcn_s_setprio(1);
    #pragma unroll
    for (int ni = 0; ni < 4; ++ni){
      const char* kr = Kc + (ni * 16 + li) * 128;
      bf16x8 k0 = *(const bf16x8*)(kr + ((g * 16) ^ swm));
      bf16x8 k1 = *(const bf16x8*)(kr + ((64 + g * 16) ^ swm));
      f32x4 a0 = zero, a1 = zero;
      a0 = __builtin_amdgcn_mfma_f32_16x16x32_bf16(k0, qa00, a0, 0, 0, 0);
      a0 = __builtin_amdgcn_mfma_f32_16x16x32_bf16(k1, qa01, a0, 0, 0, 0);
      a1 = __builtin_amdgcn_mfma_f32_16x16x32_bf16(k0, qa10, a1, 0, 0, 0);
      a1 = __builtin_amdgcn_mfma_f32_16x16x32_bf16(k1, qa11, a1, 0, 0, 0);
      sc[0][ni] = a0; sc[1][ni] = a1;
    }
    __builtin_amdgcn_s_setprio(0);

    // per-panel: P = exp2(S') -> truncation pack -> per-wave LDS -> P frags
    char* pbase = (char*)&PT[w][0];
    bf16x8 pbr0[2], pbr1[2];
    #pragma unroll
    for (int mi = 0; mi < 2; ++mi){
      char* pbw = pbase + li * 128;
      #pragma unroll
      for (int ni = 0; ni < 4; ++ni){
        float p0 = fast_exp2(sc[mi][ni][0]);
        float p1 = fast_exp2(sc[mi][ni][1]);
        float p2 = fast_exp2(sc[mi][ni][2]);
        float p3 = fast_exp2(sc[mi][ni][3]);
        uint2 u;
        u.x = bfpack_tr(p0, p1);
        u.y = bfpack_tr(p2, p3);
        *(uint2*)(pbw + ((ni * 32 + g * 8) ^ swm)) = u;   // ds_write_b64
      }
      // read this panel's B-frags before next panel overwrites the buffer
      // (same-wave DS ops execute in order)
      if (mi == 0){
        pbr0[0] = *(const bf16x8*)(pbase + li * 128 + ((g * 16) ^ swm));
        pbr0[1] = *(const bf16x8*)(pbase + li * 128 + ((64 + g * 16) ^ swm));
      } else {
        pbr1[0] = *(const bf16x8*)(pbase + li * 128 + ((g * 16) ^ swm));
        pbr1[1] = *(const bf16x8*)(pbase + li * 128 + ((64 + g * 16) ^ swm));
      }
    }

    // PV: ctx^T += V^T . P^T  (V frags read once, used by both panels);
    // l += ones . P^T
    __builtin_amdgcn_s_setprio(1);
    #pragma unroll
    for (int kk = 0; kk < 2; ++kk){
      bf16x8 pb0 = kk ? pbr0[1] : pbr0[0];
      bf16x8 pb1 = kk ? pbr1[1] : pbr1[0];
      lacc0 = __builtin_amdgcn_mfma_f32_16x16x32_bf16(ones, pb0, lacc0, 0, 0, 0);
      lacc1 = __builtin_amdgcn_mfma_f32_16x16x32_bf16(ones, pb1, lacc1, 0, 0, 0);
      #pragma unroll
      for (int md = 0; md < 4; ++md){
        int d = md * 16 + li;
        bf16x8 va = *(const bf16x8*)(Vc + d * 128 + ((kk * 64 + g * 16) ^ ((d & 7) << 4)));
        oc[md][0] = __builtin_amdgcn_mfma_f32_16x16x32_bf16(va, pb0, oc[md][0], 0, 0, 0);
        oc[md][1] = __builtin_amdgcn_mfma_f32_16x16x32_bf16(va, pb1, oc[md][1], 0, 0, 0);
      }
    }
    __builtin_amdgcn_s_setprio(0);
    asm volatile("s_waitcnt lgkmcnt(0)" ::: "memory");  // my LDS reads complete
    asm volatile("s_barrier" ::: "memory");   // B: safe to overwrite KT/VT[cur]
  }

  // epilogue: ctx^T (row=d, col=q=li), scale by 1/l (all lacc regs equal)
  float rl0 = 1.f / lacc0[0], rl1 = 1.f / lacc1[0];
  int b = bh >> 4, h = bh & 15;
  long obase = ((long)b * 2048 + qt * 128 + w * 32) * 1024 + h * 64;
  #pragma unroll
  for (int md = 0; md < 4; ++md){
    int d0 = md * 16 + g * 4;
    f32x4 v0 = oc[md][0] * rl0;
    f32x4 v1 = oc[md][1] * rl1;
    *(f32x4*)(out + obase + (long)li * 1024 + d0) = v0;
    *(f32x4*)(out + obase + (long)(16 + li) * 1024 + d0) = v1;
  }
}

// ---------------- launch ----------------
extern "C" void kernel_launch(void* const* d_in, const int* in_sizes, int n_in,
                              void* d_out, int out_size, void* d_ws, size_t ws_size,
                              hipStream_t stream){
  const float* hs  = (const float*)d_in[0];
  const float* Wq  = (const float*)d_in[1];
  const float* bq  = (const float*)d_in[2];
  const float* Wk  = (const float*)d_in[3];
  const float* bk  = (const float*)d_in[4];
  const float* Wv  = (const float*)d_in[5];
  const float* bvv = (const float*)d_in[6];
  float* out = (float*)d_out;
  char* ws = (char*)d_ws;

  u16*    hsb = (u16*)(ws);                 // 16 MB  bf16 hidden
  u16*    Wt  = (u16*)(ws + 16777216);      //  6 MB  bf16 W^T x3
  u16*    Qb  = (u16*)(ws + 23068672);      // 16 MB  Q  [bh][s][d]
  u16*    Kb  = (u16*)(ws + 39845888);      // 16 MB  K  [bh][s][d]
  u16*    Vt  = (u16*)(ws + 56623104);      // 16 MB  V^T[bh][d][s]
  float2* cs  = (float2*)(ws + 73400320);   //  1 MB  rope table

  k_conv_hs<<<dim3(2048), dim3(256), 0, stream>>>(hs, hsb, 2097152, cs);
  k_trans_w<<<dim3(32, 32, 3), dim3(32, 8), 0, stream>>>(Wq, Wk, Wv, Wt);
  k_qkv<<<dim3(8, 64, 3), dim3(256), 0, stream>>>(hsb, Wt, bq, bk, bvv, cs, Qb, Kb, Vt);
  k_attn<<<dim3(16, 64), dim3(256), 0, stream>>>(Qb, Kb, Vt, out);
}

// Round 20
// 162.282 us; speedup vs baseline: 1.0104x; 1.0080x over previous
//
#include <hip/hip_runtime.h>
#include <hip/hip_bf16.h>

typedef __attribute__((ext_vector_type(8))) short bf16x8;
typedef __attribute__((ext_vector_type(4))) float f32x4;
typedef unsigned short u16;

#define DEVI __device__ __forceinline__

DEVI u16 f2bf(float f){
  unsigned int u = __float_as_uint(f);
  u += 0x7FFF + ((u >> 16) & 1);
  return (u16)(u >> 16);
}

// TRUNCATION bf16 pair pack: {hi:trunc-bf(b), lo:trunc-bf(a)} — single v_perm.
// Used ONLY for P: l is computed from the same truncated P (ones-MFMA), so
// the common-mode truncation bias cancels exactly in the P/l ratio.
DEVI unsigned int bfpack_tr(float a, float b){
  return __builtin_amdgcn_perm(__float_as_uint(b), __float_as_uint(a), 0x07060302u);
}

DEVI float fast_exp2(float x){
#if __has_builtin(__builtin_amdgcn_exp2f)
  return __builtin_amdgcn_exp2f(x);
#else
  return exp2f(x);
#endif
}

// async global->LDS, 16B per lane; LDS dest = wave-uniform base + lane*16
DEVI void gload16(const u16* g, u16* l){
  __builtin_amdgcn_global_load_lds((const __attribute__((address_space(1))) void*)g,
                                   (__attribute__((address_space(3))) void*)l, 16, 0, 0);
}

// ---------------- prep kernels ----------------

// hs f32 -> bf16 conversion; first 131072 threads also fill the rope table
// cs[s*64+d] = {cos, sin} of s * 10000^(-(d%32)/32).  [s][d] layout: epilogue
// loads have d = li varying across lanes -> 128B-contiguous per 16-lane group.
__global__ __launch_bounds__(256) void k_conv_hs(const float* __restrict__ src,
                                                 u16* __restrict__ dst, int n4,
                                                 float2* __restrict__ cs){
  int idx = blockIdx.x * blockDim.x + threadIdx.x;
  int stride = gridDim.x * blockDim.x;
  for (int i = idx; i < n4; i += stride){
    float4 v = ((const float4*)src)[i];
    ushort4 o;
    o.x = f2bf(v.x); o.y = f2bf(v.y); o.z = f2bf(v.z); o.w = f2bf(v.w);
    ((ushort4*)dst)[i] = o;
  }
  if (idx < 131072){                       // 2048*64 rope entries
    int d = idx & 63, s = idx >> 6;
    int i = d & 31;
    float invf = __expf(-(float)i / 32.f * 9.210340371976184f);
    float ang = (float)s * invf;
    cs[idx] = make_float2(cosf(ang), sinf(ang));
  }
}

// W [k][n] f32  ->  Wt [n][k] bf16   (3 matrices)
__global__ __launch_bounds__(256) void k_trans_w(const float* __restrict__ w0,
    const float* __restrict__ w1, const float* __restrict__ w2, u16* __restrict__ Wt){
  __shared__ float t[32][33];
  int z = blockIdx.z;
  const float* W = z == 0 ? w0 : (z == 1 ? w1 : w2);
  u16* dst = Wt + z * 1048576;
  int tx = threadIdx.x, ty = threadIdx.y;
  int n = blockIdx.x * 32 + tx;
  for (int j = 0; j < 4; ++j){
    int k = blockIdx.y * 32 + ty + j * 8;
    t[ty + j * 8][tx] = W[k * 1024 + n];
  }
  __syncthreads();
  for (int j = 0; j < 4; ++j){
    int nrow = blockIdx.x * 32 + ty + j * 8;
    int kcol = blockIdx.y * 32 + tx;
    dst[nrow * 1024 + kcol] = f2bf(t[tx][ty + j * 8]);
  }
}

// ---------------- QKV projection GEMM ----------------
// m97 structure + bijective XCD swizzle (T1): each XCD owns an 8-m-tile strip
// (2MB A, L2-resident); within XCD iterate m fastest, then n, then which.
__global__ __launch_bounds__(256) void k_qkv(const u16* __restrict__ hsb,
    const u16* __restrict__ Wt, const float* __restrict__ biasq,
    const float* __restrict__ biask, const float* __restrict__ biasv,
    const float2* __restrict__ cs,
    u16* __restrict__ Qb, u16* __restrict__ Kb, u16* __restrict__ Vt){
  __shared__ u16 At[128 * 64];
  __shared__ u16 Bt[128 * 64];
  // lin = x + 8y + 512z; xcd = lin&7 (HW round-robin); q orders blocks in time
  int lin = blockIdx.x + (blockIdx.y << 3) + (blockIdx.z << 9);
  int xcd = lin & 7, q = lin >> 3;
  int mi_ = q & 7, rest = q >> 3;
  int which = rest >> 3;
  int m0 = (xcd * 8 + mi_) * 128;
  int n0 = (rest & 7) * 128;
  const u16* Wb = Wt + which * 1048576;
  int tid = threadIdx.x, lane = tid & 63, wid = tid >> 6, g = lane >> 4, li = lane & 15;
  int wrow = (wid >> 1) * 64, wcol = (wid & 1) * 64;
  int kvr = lane >> 3;            // row within an 8-row segment
  int gsl = (lane & 7) ^ kvr;     // pre-swizzled 16B slot in the 128B row
  f32x4 zero = {0.f, 0.f, 0.f, 0.f};
  f32x4 acc[4][4];
  for (int i = 0; i < 4; ++i) for (int j = 0; j < 4; ++j) acc[i][j] = zero;

  for (int kt = 0; kt < 16; ++kt){
    #pragma unroll
    for (int i = 0; i < 4; ++i){
      int seg = wid * 4 + i;             // 0..15, 8 rows each
      int row = seg * 8 + kvr;
      gload16(hsb + (m0 + row) * 1024 + kt * 64 + gsl * 8, At + seg * 512);
      gload16(Wb  + (n0 + row) * 1024 + kt * 64 + gsl * 8, Bt + seg * 512);
    }
    __syncthreads();                     // drains vmcnt -> tiles ready
    #pragma unroll
    for (int kk = 0; kk < 2; ++kk){
      bf16x8 af[4], bfr[4];
      #pragma unroll
      for (int i = 0; i < 4; ++i){
        int row = wrow + i * 16 + li;
        af[i] = *(const bf16x8*)((char*)At + row * 128 + ((kk * 64 + g * 16) ^ ((row & 7) << 4)));
        int col = wcol + i * 16 + li;
        bfr[i] = *(const bf16x8*)((char*)Bt + col * 128 + ((kk * 64 + g * 16) ^ ((col & 7) << 4)));
      }
      #pragma unroll
      for (int i = 0; i < 4; ++i)
        #pragma unroll
        for (int j = 0; j < 4; ++j)
          acc[i][j] = __builtin_amdgcn_mfma_f32_16x16x32_bf16(af[i], bfr[j], acc[i][j], 0, 0, 0);
    }
    __syncthreads();                     // all reads done before next stage
  }

  // epilogue
  const float* bias = which == 0 ? biasq : (which == 1 ? biask : biasv);
  int b = m0 >> 11;                      // batch (block never straddles)
  int hbase = (n0 + wcol) >> 6;          // head
  float vals[4][4][4];
  for (int i = 0; i < 4; ++i)
    for (int j = 0; j < 4; ++j){
      float bb = bias[n0 + wcol + j * 16 + li];
      for (int r = 0; r < 4; ++r){
        float v = acc[i][j][r] + bb;
        // q: hd^-0.5 pre-scale * 1/sqrt(hd) * log2(e)  (exp -> exp2 downstream)
        if (which == 0) v *= 0.015625f * 1.4426950408889634f;
        vals[i][j][r] = v;
      }
    }
  if (which < 2){
    u16* dst = which == 0 ? Qb : Kb;
    for (int i = 0; i < 4; ++i)
      for (int j = 0; j < 4; ++j)
        for (int r = 0; r < 4; ++r){
          int m = m0 + wrow + i * 16 + g * 4 + r;
          int srow = m & 2047;
          int d = j * 16 + li;
          float2 c2 = cs[srow * 64 + d];
          float part = vals[i][j ^ 2][r];           // partner col d^32 (same lane)
          float o = vals[i][j][r] * c2.x + (d < 32 ? -part : part) * c2.y;
          dst[(((long)b * 16 + hbase) * 2048 + srow) * 64 + d] = f2bf(o);
        }
  } else {
    for (int i = 0; i < 4; ++i)
      for (int j = 0; j < 4; ++j){
        int sbase = (m0 + wrow + i * 16 + g * 4) & 2047;
        int d = j * 16 + li;
        ushort4 pk;
        pk.x = f2bf(vals[i][j][0]); pk.y = f2bf(vals[i][j][1]);
        pk.z = f2bf(vals[i][j][2]); pk.w = f2bf(vals[i][j][3]);
        *(ushort4*)(Vt + (((long)b * 16 + hbase) * 64 + d) * 2048 + sbase) = pk;
      }
  }
}

// ---------------- attention ----------------
// Session-best structure (round 16: 162.4us total). Unnormalized softmax
// (S = q.k/64, |S| << 1, fp32 exp overflow-safe): no max tracking, no
// rescale. P = exp2(S') with log2e folded into Q upstream. K+V staged via
// global_load_lds (coalesced 1KB/wave -- REQUIRED for inter-block L2
// sharing), double-buffered; counted-vmcnt two-barrier schedule (vmcnt(4)
// waits only for stage(t), issued a full tile ago; barrier A = cross-wave
// landed; lgkmcnt(0)+barrier B = safe to overwrite). P packed by TRUNCATION
// (single v_perm; bias cancels in P/l), round-trips through one shared 2KB
// per-wave LDS buffer. V frags read once per tile. l via ones-row MFMA.
__global__ __launch_bounds__(256, 4) void k_attn(const u16* __restrict__ Qb,
    const u16* __restrict__ Kb, const u16* __restrict__ Vt, float* __restrict__ out){
  __shared__ u16 KT[2][64 * 64];      // [buf][kv(64)][d(64)]  8KB each
  __shared__ u16 VT[2][64 * 64];      // [buf][d(64)][kv(64)]  8KB each
  __shared__ u16 PT[4][1024];         // per wave: [q(16)][kv(64)] 2KB, shared mi
  // XCD swizzle: all 16 q-tile blocks of one head land on one XCD
  int lin = blockIdx.y * 16 + blockIdx.x;
  int swzb = ((lin & 7) << 7) + (lin >> 3);
  int qt = swzb & 15, bh = swzb >> 4;
  int tid = threadIdx.x, lane = tid & 63, w = tid >> 6, g = lane >> 4, li = lane & 15;
  int swm = (li & 7) << 4;
  int kvr = lane >> 3;
  int gsl = (lane & 7) ^ kvr;
  int seg0 = w * 2, seg1 = w * 2 + 1;

  const u16* Qp = Qb + ((long)bh * 2048 + qt * 128 + w * 32) * 64;
  bf16x8 qa00 = *(const bf16x8*)(Qp + li * 64 + g * 8);
  bf16x8 qa01 = *(const bf16x8*)(Qp + li * 64 + 32 + g * 8);
  bf16x8 qa10 = *(const bf16x8*)(Qp + (16 + li) * 64 + g * 8);
  bf16x8 qa11 = *(const bf16x8*)(Qp + (16 + li) * 64 + 32 + g * 8);

  const u16* Kp = Kb + (long)bh * 131072;
  const u16* Vp = Vt + (long)bh * 131072;

  f32x4 zero = {0.f, 0.f, 0.f, 0.f};
  f32x4 oc[4][2];
  for (int i = 0; i < 4; ++i){ oc[i][0] = zero; oc[i][1] = zero; }
  f32x4 lacc0 = zero, lacc1 = zero;   // ones-row MFMA accumulators (l for q=li)
  bf16x8 ones;
  #pragma unroll
  for (int i = 0; i < 8; ++i) ones[i] = (short)0x3F80;  // bf16 1.0

  auto STAGE = [&](int t, int c){
    const u16* kbase = Kp + t * 4096;
    const u16* vbase = Vp + t * 64;
    gload16(kbase + (seg0 * 8 + kvr) * 64 + gsl * 8, &KT[c][seg0 * 512]);
    gload16(kbase + (seg1 * 8 + kvr) * 64 + gsl * 8, &KT[c][seg1 * 512]);
    gload16(vbase + (seg0 * 8 + kvr) * 2048 + gsl * 8, &VT[c][seg0 * 512]);
    gload16(vbase + (seg1 * 8 + kvr) * 2048 + gsl * 8, &VT[c][seg1 * 512]);
  };

  STAGE(0, 0);

  for (int t = 0; t < 32; ++t){
    int cur = t & 1;
    if (t < 31){
      STAGE(t + 1, cur ^ 1);
      // wait for OWN stage(t) (issued a full tile ago); stage(t+1) stays in flight
      asm volatile("s_waitcnt vmcnt(4)" ::: "memory");
    } else {
      asm volatile("s_waitcnt vmcnt(0)" ::: "memory");
    }
    asm volatile("s_barrier" ::: "memory");   // A: all waves' stage(t) landed

    const char* Kc = (const char*)&KT[cur][0];
    const char* Vc = (const char*)&VT[cur][0];

    // QK^T (swapped): sc[mi][ni][r] = S'[kv = ni*16+g*4+r][q = li]
    f32x4 sc[2][4];
    __builtin_amdgcn_s_setprio(1);
    #pragma unroll
    for (int ni = 0; ni < 4; ++ni){
      const char* kr = Kc + (ni * 16 + li) * 128;
      bf16x8 k0 = *(const bf16x8*)(kr + ((g * 16) ^ swm));
      bf16x8 k1 = *(const bf16x8*)(kr + ((64 + g * 16) ^ swm));
      f32x4 a0 = zero, a1 = zero;
      a0 = __builtin_amdgcn_mfma_f32_16x16x32_bf16(k0, qa00, a0, 0, 0, 0);
      a0 = __builtin_amdgcn_mfma_f32_16x16x32_bf16(k1, qa01, a0, 0, 0, 0);
      a1 = __builtin_amdgcn_mfma_f32_16x16x32_bf16(k0, qa10, a1, 0, 0, 0);
      a1 = __builtin_amdgcn_mfma_f32_16x16x32_bf16(k1, qa11, a1, 0, 0, 0);
      sc[0][ni] = a0; sc[1][ni] = a1;
    }
    __builtin_amdgcn_s_setprio(0);

    // per-panel: P = exp2(S') -> truncation pack -> per-wave LDS -> P frags
    char* pbase = (char*)&PT[w][0];
    bf16x8 pbr0[2], pbr1[2];
    #pragma unroll
    for (int mi = 0; mi < 2; ++mi){
      char* pbw = pbase + li * 128;
      #pragma unroll
      for (int ni = 0; ni < 4; ++ni){
        float p0 = fast_exp2(sc[mi][ni][0]);
        float p1 = fast_exp2(sc[mi][ni][1]);
        float p2 = fast_exp2(sc[mi][ni][2]);
        float p3 = fast_exp2(sc[mi][ni][3]);
        uint2 u;
        u.x = bfpack_tr(p0, p1);
        u.y = bfpack_tr(p2, p3);
        *(uint2*)(pbw + ((ni * 32 + g * 8) ^ swm)) = u;   // ds_write_b64
      }
      // read this panel's B-frags before next panel overwrites the buffer
      // (same-wave DS ops execute in order)
      if (mi == 0){
        pbr0[0] = *(const bf16x8*)(pbase + li * 128 + ((g * 16) ^ swm));
        pbr0[1] = *(const bf16x8*)(pbase + li * 128 + ((64 + g * 16) ^ swm));
      } else {
        pbr1[0] = *(const bf16x8*)(pbase + li * 128 + ((g * 16) ^ swm));
        pbr1[1] = *(const bf16x8*)(pbase + li * 128 + ((64 + g * 16) ^ swm));
      }
    }

    // PV: ctx^T += V^T . P^T  (V frags read once, used by both panels);
    // l += ones . P^T
    __builtin_amdgcn_s_setprio(1);
    #pragma unroll
    for (int kk = 0; kk < 2; ++kk){
      bf16x8 pb0 = kk ? pbr0[1] : pbr0[0];
      bf16x8 pb1 = kk ? pbr1[1] : pbr1[0];
      lacc0 = __builtin_amdgcn_mfma_f32_16x16x32_bf16(ones, pb0, lacc0, 0, 0, 0);
      lacc1 = __builtin_amdgcn_mfma_f32_16x16x32_bf16(ones, pb1, lacc1, 0, 0, 0);
      #pragma unroll
      for (int md = 0; md < 4; ++md){
        int d = md * 16 + li;
        bf16x8 va = *(const bf16x8*)(Vc + d * 128 + ((kk * 64 + g * 16) ^ ((d & 7) << 4)));
        oc[md][0] = __builtin_amdgcn_mfma_f32_16x16x32_bf16(va, pb0, oc[md][0], 0, 0, 0);
        oc[md][1] = __builtin_amdgcn_mfma_f32_16x16x32_bf16(va, pb1, oc[md][1], 0, 0, 0);
      }
    }
    __builtin_amdgcn_s_setprio(0);
    asm volatile("s_waitcnt lgkmcnt(0)" ::: "memory");  // my LDS reads complete
    asm volatile("s_barrier" ::: "memory");   // B: safe to overwrite KT/VT[cur]
  }

  // epilogue: ctx^T (row=d, col=q=li), scale by 1/l (all lacc regs equal)
  float rl0 = 1.f / lacc0[0], rl1 = 1.f / lacc1[0];
  int b = bh >> 4, h = bh & 15;
  long obase = ((long)b * 2048 + qt * 128 + w * 32) * 1024 + h * 64;
  #pragma unroll
  for (int md = 0; md < 4; ++md){
    int d0 = md * 16 + g * 4;
    f32x4 v0 = oc[md][0] * rl0;
    f32x4 v1 = oc[md][1] * rl1;
    *(f32x4*)(out + obase + (long)li * 1024 + d0) = v0;
    *(f32x4*)(out + obase + (long)(16 + li) * 1024 + d0) = v1;
  }
}

// ---------------- launch ----------------
extern "C" void kernel_launch(void* const* d_in, const int* in_sizes, int n_in,
                              void* d_out, int out_size, void* d_ws, size_t ws_size,
                              hipStream_t stream){
  const float* hs  = (const float*)d_in[0];
  const float* Wq  = (const float*)d_in[1];
  const float* bq  = (const float*)d_in[2];
  const float* Wk  = (const float*)d_in[3];
  const float* bk  = (const float*)d_in[4];
  const float* Wv  = (const float*)d_in[5];
  const float* bvv = (const float*)d_in[6];
  float* out = (float*)d_out;
  char* ws = (char*)d_ws;

  u16*    hsb = (u16*)(ws);                 // 16 MB  bf16 hidden
  u16*    Wt  = (u16*)(ws + 16777216);      //  6 MB  bf16 W^T x3
  u16*    Qb  = (u16*)(ws + 23068672);      // 16 MB  Q  [bh][s][d]
  u16*    Kb  = (u16*)(ws + 39845888);      // 16 MB  K  [bh][s][d]
  u16*    Vt  = (u16*)(ws + 56623104);      // 16 MB  V^T[bh][d][s]
  float2* cs  = (float2*)(ws + 73400320);   //  1 MB  rope table

  k_conv_hs<<<dim3(2048), dim3(256), 0, stream>>>(hs, hsb, 2097152, cs);
  k_trans_w<<<dim3(32, 32, 3), dim3(32, 8), 0, stream>>>(Wq, Wk, Wv, Wt);
  k_qkv<<<dim3(8, 64, 3), dim3(256), 0, stream>>>(hsb, Wt, bq, bk, bvv, cs, Qb, Kb, Vt);
  k_attn<<<dim3(16, 64), dim3(256), 0, stream>>>(Qb, Kb, Vt, out);
}